// Round 3
// baseline (217.758 us; speedup 1.0000x reference)
//
#include <hip/hip_runtime.h>
#include <stdint.h>

// ---------- types ----------
typedef __bf16    bf16x8 __attribute__((ext_vector_type(8)));
typedef float     f32x4  __attribute__((ext_vector_type(4)));
typedef uint32_t  u32x4  __attribute__((ext_vector_type(4)));

#define MFMA(a,b,c) __builtin_amdgcn_mfma_f32_16x16x32_bf16((a),(b),(c),0,0,0)

// ---------- persistent device scratch (bf16 internal pipeline) ----------
__device__ __align__(16) uint16_t g_y [8*64*64*256];
__device__ __align__(16) uint16_t g_ao[8*64*64*256];
__device__ __align__(16) uint16_t g_ch[8*64*64*256];
__device__ __align__(16) uint16_t g_wpk[393216];

#define WQF 0
#define WKF 65536
#define WVF 131072
#define WCF 196608
#define W1F 262144
#define W2F 294912
#define WPF 327680

static __device__ __forceinline__ float b2f(uint32_t u){ return __builtin_bit_cast(float, u<<16); }
static __device__ __forceinline__ uint32_t f2b(float f){
  uint32_t x = __builtin_bit_cast(uint32_t, f);
  return (x + 0x7fffu + ((x>>16)&1u)) >> 16;   // RNE bf16
}

// ---------- kernel 0: repack fp32 weights into bf16 B-fragment-major layout ----------
// frag element: W[nt*16 + (lane&15)][s*32 + (lane>>4)*8 + j] at ((nt*S+s)*64+lane)*8+j
__global__ __launch_bounds__(256) void kpack(const float* __restrict__ Wqkv,
    const float* __restrict__ W1, const float* __restrict__ W2,
    const float* __restrict__ Wp){
  int idx = blockIdx.x*256 + threadIdx.x;
  int j = idx & 7, lane = (idx>>3)&63;
  int n16 = lane & 15, q4 = lane>>4;
  float v;
  if (idx < 262144){                 // q,k,v,chans from interleaved W_qkv (row o = 4c+t)
    int t = idx >> 16, l = idx & 65535;
    int s = (l>>9)&7, nt = l>>12;
    v = Wqkv[(4*(nt*16+n16) + t)*256 + s*32 + q4*8 + j];
  } else if (idx < 294912){          // W1 [128][256]
    int l = idx - 262144;
    int s = (l>>9)&7, nt = l>>12;
    v = W1[(nt*16+n16)*256 + s*32 + q4*8 + j];
  } else if (idx < 327680){          // W2 [256][128], S=4
    int l = idx - 294912;
    int s = (l>>9)&3, nt = l>>11;
    v = W2[(nt*16+n16)*128 + s*32 + q4*8 + j];
  } else {                           // Wp [256][256]
    int l = idx - 327680;
    int s = (l>>9)&7, nt = l>>12;
    v = Wp[(nt*16+n16)*256 + s*32 + q4*8 + j];
  }
  g_wpk[idx] = (uint16_t)f2b(v);
}

// ---------- kernel 1: 3x3 avg pool (stride 1, pad 1, /9) + NCHW->[pix][C], fp32 in ----------
__global__ __launch_bounds__(512) void kpool(const float* __restrict__ x){
  __shared__ __align__(16) uint16_t sm[3*256*82];
  uint32_t* smw = (uint32_t*)sm;
  int t = threadIdx.x;
  int b = blockIdx.x >> 6, h = blockIdx.x & 63;
  for (int i=t; i<3*256*41; i+=512) smw[i] = 0;
  __syncthreads();
  #pragma unroll
  for (int i=0;i<24;i++){
    int id = t + 512*i;                       // 12288 chunks of 4 fp32 elems
    int w4 = id&15, c = (id>>4)&255, hh = id>>12;
    int gy = h - 1 + hh;
    if ((unsigned)gy < 64u){
      f32x4 ld = *(const f32x4*)&x[(((b*256+c)*64+gy)*64) + w4*4];
      int wb = (((hh*256+c)*82 + 8 + w4*4) >> 1);
      smw[wb+0] = f2b(ld[0]) | (f2b(ld[1])<<16);
      smw[wb+1] = f2b(ld[2]) | (f2b(ld[3])<<16);
    }
  }
  __syncthreads();
  int c = t & 255, wsel = t >> 8;
  int r0 = c*82, r1 = r0 + 256*82, r2 = r1 + 256*82;
  int w0 = wsel*32;
  float csp = b2f(sm[r0+w0+7]) + b2f(sm[r1+w0+7]) + b2f(sm[r2+w0+7]);
  float csc = b2f(sm[r0+w0+8]) + b2f(sm[r1+w0+8]) + b2f(sm[r2+w0+8]);
  uint16_t* dst = g_y + ((b*64+h)*64)*256 + c;
  for (int j2=0;j2<32;j2++){
    int w = w0 + j2;
    float csn = b2f(sm[r0+w+9]) + b2f(sm[r1+w+9]) + b2f(sm[r2+w+9]);
    float yv = (csp + csc + csn) * (1.0f/9.0f);
    dst[w*256] = (uint16_t)f2b(yv);
    csp = csc; csc = csn;
  }
}

// ---------- kernel 2: fused qkv GEMMs + 3x3 window attention + chans GEMM ----------
#define YSTR 264
#define HSTR 134
#define K2_QS 26400
#define K2_KS 34976
#define K2_VS 48376
__global__ __launch_bounds__(512,2) void kattn(const float* __restrict__ bqkv){
  __shared__ __align__(16) uint16_t sm[61776];   // 123.5 KB
  int t = threadIdx.x;
  int lane = t & 63, wave = t >> 6;
  int n16 = lane & 15, quad = lane >> 4;
  int bb = blockIdx.x >> 6, ty = (blockIdx.x>>3)&7, tx = blockIdx.x & 7;

  // --- zero-init ALL LDS ---
  {
    uint32_t* smw = (uint32_t*)sm;
    for (int i=t; i<30888; i+=512) smw[i] = 0;
  }
  __syncthreads();

  // --- load 10x10 y-halo (zero outside image) ---
  #pragma unroll
  for (int i=0;i<7;i++){
    int id = t + 512*i;
    if (id < 3200){
      int hp = id >> 5, c8 = id & 31;
      int py = hp/10, px = hp - py*10;
      int gy = ty*8 + py - 1, gx = tx*8 + px - 1;
      u32x4 ld = {0,0,0,0};
      if ((unsigned)gy<64u && (unsigned)gx<64u)
        ld = *(const u32x4*)&g_y[((bb*64+gy)*64+gx)*256 + c8*8];
      *(u32x4*)&sm[hp*YSTR + c8*8] = ld;
    }
  }
  __syncthreads();

  for (int hf=0; hf<2; hf++){
    // ---- q GEMM: M=64 interior, N=128 (this half) ----
    {
      int ntg = hf*8 + wave;
      bf16x8 Bq[8];
      #pragma unroll
      for (int s=0;s<8;s++) Bq[s] = *(const bf16x8*)&g_wpk[WQF + ((ntg*8+s)*64+lane)*8];
      float bq = bqkv[4*(ntg*16+n16) + 0];
      int colB = wave*16;
      #pragma unroll
      for (int mt=0; mt<4; mt++){
        f32x4 a = {0.f,0.f,0.f,0.f};
        int m = mt*16 + n16;
        int hrow = 10*(m>>3) + (m&7) + 11;     // interior -> halo row
        #pragma unroll
        for (int s=0;s<8;s++){
          bf16x8 A = *(const bf16x8*)&sm[hrow*YSTR + s*32 + quad*8];
          a = MFMA(A, Bq[s], a);
        }
        #pragma unroll
        for (int r=0;r<4;r++){
          int row = mt*16 + quad*4 + r;
          sm[K2_QS + row*HSTR + colB + n16] = (uint16_t)f2b(a[r] + bq);
        }
      }
    }
    __syncthreads();
    // ---- k & v GEMM (shared A-frags): M=112 halo (rows>=100 clamped), N=128 ----
    {
      int ntg = hf*8 + wave;
      bf16x8 Bk[8], Bv[8];
      #pragma unroll
      for (int s=0;s<8;s++){
        Bk[s] = *(const bf16x8*)&g_wpk[WKF + ((ntg*8+s)*64+lane)*8];
        Bv[s] = *(const bf16x8*)&g_wpk[WVF + ((ntg*8+s)*64+lane)*8];
      }
      float bk = bqkv[4*(ntg*16+n16) + 1];
      float bv = bqkv[4*(ntg*16+n16) + 2];
      int colB = wave*16;
      #pragma unroll
      for (int mt=0; mt<7; mt++){
        f32x4 ak = {0.f,0.f,0.f,0.f}, av = {0.f,0.f,0.f,0.f};
        int m = mt*16 + n16;
        int mr = (m < 100) ? m : 99;            // clamp: never read past halo
        #pragma unroll
        for (int s=0;s<8;s++){
          bf16x8 A = *(const bf16x8*)&sm[mr*YSTR + s*32 + quad*8];
          ak = MFMA(A, Bk[s], ak);
          av = MFMA(A, Bv[s], av);
        }
        #pragma unroll
        for (int r=0;r<4;r++){
          int row = mt*16 + quad*4 + r;
          if (row < 100){
            int py = row/10, px = row - py*10;
            int gy = ty*8 + py - 1, gx = tx*8 + px - 1;
            bool ok = ((unsigned)gy<64u) && ((unsigned)gx<64u);
            float vk = ok ? ak[r] + bk : 0.f;   // zero k,v outside image (unfold pad)
            float vv = ok ? av[r] + bv : 0.f;
            sm[K2_KS + row*HSTR + colB + n16] = (uint16_t)f2b(vk);
            sm[K2_VS + row*HSTR + colB + n16] = (uint16_t)f2b(vv);
          }
        }
      }
    }
    __syncthreads();
    // ---- attention: thread = (pixel, head-in-half); softmax over all 9 (incl. zeros) ----
    if (t < 256){
      int p = t & 63, hl = t >> 6;
      int iy = p >> 3, ix = p & 7;
      int cb = hl*32;
      const uint32_t* q32 = (const uint32_t*)&sm[K2_QS + p*HSTR + cb];
      float qv[32];
      #pragma unroll
      for (int i=0;i<16;i++){ uint32_t u=q32[i]; qv[2*i]=b2f(u&0xffffu); qv[2*i+1]=b2f(u>>16); }
      int hb = (iy+1)*10 + ix + 1;
      const int off[9] = {-11,-10,-9,-1,0,1,9,10,11};
      float sc[9];
      #pragma unroll
      for (int nb=0;nb<9;nb++){
        const uint32_t* k32 = (const uint32_t*)&sm[K2_KS + (hb+off[nb])*HSTR + cb];
        float s = 0.f;
        #pragma unroll
        for (int i=0;i<16;i++){ uint32_t u=k32[i]; s += qv[2*i]*b2f(u&0xffffu) + qv[2*i+1]*b2f(u>>16); }
        sc[nb] = s * 0.17677669529663687f;      // 1/sqrt(32)
      }
      float mx = sc[0];
      #pragma unroll
      for (int nb=1;nb<9;nb++) mx = fmaxf(mx, sc[nb]);
      float l = 0.f;
      #pragma unroll
      for (int nb=0;nb<9;nb++){ sc[nb] = __expf(sc[nb]-mx); l += sc[nb]; }
      float inv = 1.f / l;
      float o[32];
      #pragma unroll
      for (int i=0;i<32;i++) o[i]=0.f;
      #pragma unroll
      for (int nb=0;nb<9;nb++){
        float wgt = sc[nb]*inv;
        const uint32_t* v32 = (const uint32_t*)&sm[K2_VS + (hb+off[nb])*HSTR + cb];
        #pragma unroll
        for (int i=0;i<16;i++){ uint32_t u=v32[i]; o[2*i] += wgt*b2f(u&0xffffu); o[2*i+1] += wgt*b2f(u>>16); }
      }
      int pg = ((bb*64 + ty*8+iy)*64 + tx*8+ix);
      uint16_t* dst = g_ao + pg*256 + hf*128 + cb;
      #pragma unroll
      for (int i=0;i<4;i++){
        u32x4 stv;
        #pragma unroll
        for (int jj=0;jj<4;jj++) stv[jj] = f2b(o[i*8+2*jj]) | (f2b(o[i*8+2*jj+1])<<16);
        *(u32x4*)&dst[i*8] = stv;
      }
    }
    __syncthreads();
  }
  // ---- chans GEMM: M=64, N=256; stage (stride 264) over dead q/k buffers ----
  #pragma unroll
  for (int jj=0;jj<2;jj++){
    int ntg = wave*2 + jj;
    bf16x8 Bc[8];
    #pragma unroll
    for (int s=0;s<8;s++) Bc[s] = *(const bf16x8*)&g_wpk[WCF + ((ntg*8+s)*64+lane)*8];
    float bc = bqkv[4*(ntg*16+n16) + 3];
    int colB = ntg*16;
    #pragma unroll
    for (int mt=0; mt<4; mt++){
      f32x4 a = {0.f,0.f,0.f,0.f};
      int m = mt*16 + n16;
      int hrow = 10*(m>>3) + (m&7) + 11;
      #pragma unroll
      for (int s=0;s<8;s++){
        bf16x8 A = *(const bf16x8*)&sm[hrow*YSTR + s*32 + quad*8];
        a = MFMA(A, Bc[s], a);
      }
      #pragma unroll
      for (int r=0;r<4;r++){
        int row = mt*16 + quad*4 + r;
        sm[K2_QS + row*264 + colB + n16] = (uint16_t)f2b(a[r] + bc);
      }
    }
  }
  __syncthreads();
  #pragma unroll
  for (int i=0;i<4;i++){
    int id = t + 512*i;                          // 2048 chunks
    int row = id >> 5, c8 = id & 31;
    u32x4 ld = *(const u32x4*)&sm[K2_QS + row*264 + c8*8];
    int iy = row>>3, ix = row&7;
    int pg = ((bb*64 + ty*8+iy)*64 + tx*8+ix);
    *(u32x4*)&g_ch[pg*256 + c8*8] = ld;
  }
}

// ---------- kernel 3: gate MLP + ao*(1+g) + projection + fp32 NCHW write ----------
#define K3_CH 0
#define K3_HS 16896
#define K3_AO 25600
__global__ __launch_bounds__(512,2) void kout(const float* __restrict__ b1,
    const float* __restrict__ b2v, const float* __restrict__ bp,
    float* __restrict__ out){
  __shared__ __align__(16) uint16_t sm[42496];   // 85 KB
  int t = threadIdx.x;
  int lane = t & 63, wave = t >> 6;
  int n16 = lane & 15, quad = lane >> 4;
  int b = blockIdx.x >> 6, h = blockIdx.x & 63;
  int pix0 = blockIdx.x * 64;                    // 64 pixels = full w-row at (b,h)
  {
    uint32_t* smw = (uint32_t*)sm;
    for (int i=t; i<21248; i+=512) smw[i] = 0;
  }
  __syncthreads();
  #pragma unroll
  for (int i=0;i<4;i++){
    int id = t + 512*i;
    int row = id >> 5, c8 = id & 31;
    *(u32x4*)&sm[K3_CH + row*264 + c8*8] = *(const u32x4*)&g_ch[(pix0+row)*256 + c8*8];
    *(u32x4*)&sm[K3_AO + row*264 + c8*8] = *(const u32x4*)&g_ao[(pix0+row)*256 + c8*8];
  }
  __syncthreads();
  // h = relu(ch @ W1^T + b1), N=128
  {
    int ntg = wave;
    bf16x8 Bf[8];
    #pragma unroll
    for (int s=0;s<8;s++) Bf[s] = *(const bf16x8*)&g_wpk[W1F + ((ntg*8+s)*64+lane)*8];
    float bs = b1[ntg*16+n16];
    int colB = wave*16;
    #pragma unroll
    for (int mt=0;mt<4;mt++){
      f32x4 a = {0.f,0.f,0.f,0.f};
      #pragma unroll
      for (int s=0;s<8;s++){
        bf16x8 A = *(const bf16x8*)&sm[K3_CH + (mt*16+n16)*264 + s*32 + quad*8];
        a = MFMA(A, Bf[s], a);
      }
      #pragma unroll
      for (int r=0;r<4;r++){
        int row = mt*16 + quad*4 + r;
        sm[K3_HS + row*136 + colB + n16] = (uint16_t)f2b(fmaxf(a[r]+bs, 0.f));
      }
    }
  }
  __syncthreads();
  // g = sigmoid(h @ W2^T + b2); t = ao*(1+g) -> K3_CH (ch is dead)
  #pragma unroll
  for (int jj=0;jj<2;jj++){
    int ntg = wave*2 + jj;
    bf16x8 Bf[4];
    #pragma unroll
    for (int s=0;s<4;s++) Bf[s] = *(const bf16x8*)&g_wpk[W2F + ((ntg*4+s)*64+lane)*8];
    float bs = b2v[ntg*16+n16];
    int colB = ntg*16;
    #pragma unroll
    for (int mt=0;mt<4;mt++){
      f32x4 a = {0.f,0.f,0.f,0.f};
      #pragma unroll
      for (int s=0;s<4;s++){
        bf16x8 A = *(const bf16x8*)&sm[K3_HS + (mt*16+n16)*136 + s*32 + quad*8];
        a = MFMA(A, Bf[s], a);
      }
      #pragma unroll
      for (int r=0;r<4;r++){
        int row = mt*16 + quad*4 + r;
        float gg = 1.f/(1.f+__expf(-(a[r] + bs)));
        float ao = b2f((uint32_t)sm[K3_AO + row*264 + colB + n16]);
        sm[K3_CH + row*264 + colB + n16] = (uint16_t)f2b(ao*(1.f+gg));
      }
    }
  }
  __syncthreads();
  // out_t = t @ Wp^T + bp -> K3_AO (ao is dead)
  #pragma unroll
  for (int jj=0;jj<2;jj++){
    int ntg = wave*2 + jj;
    bf16x8 Bf[8];
    #pragma unroll
    for (int s=0;s<8;s++) Bf[s] = *(const bf16x8*)&g_wpk[WPF + ((ntg*8+s)*64+lane)*8];
    float bs = bp[ntg*16+n16];
    int colB = ntg*16;
    #pragma unroll
    for (int mt=0;mt<4;mt++){
      f32x4 a = {0.f,0.f,0.f,0.f};
      #pragma unroll
      for (int s=0;s<8;s++){
        bf16x8 A = *(const bf16x8*)&sm[K3_CH + (mt*16+n16)*264 + s*32 + quad*8];
        a = MFMA(A, Bf[s], a);
      }
      #pragma unroll
      for (int r=0;r<4;r++){
        int row = mt*16 + quad*4 + r;
        sm[K3_AO + row*264 + colB + n16] = (uint16_t)f2b(a[r]+bs);
      }
    }
  }
  __syncthreads();
  // fp32 transpose write: out[b][c][h][w], lanes sweep w for coalescing
  #pragma unroll
  for (int i=0;i<8;i++){
    int idx = t + 512*i;                // 4096 float4-chunks: 256 c x 16 w-chunks
    int c = idx >> 4, wc = idx & 15;
    f32x4 stv;
    #pragma unroll
    for (int j=0;j<4;j++) stv[j] = b2f((uint32_t)sm[K3_AO + (wc*4+j)*264 + c]);
    *(f32x4*)&out[(((b*256)+c)*64 + h)*64 + wc*4] = stv;
  }
}

extern "C" void kernel_launch(void* const* d_in, const int* in_sizes, int n_in,
                              void* d_out, int out_size, void* d_ws, size_t ws_size,
                              hipStream_t stream){
  (void)in_sizes; (void)n_in; (void)d_ws; (void)ws_size; (void)out_size;
  const float* x    = (const float*)d_in[0];
  const float* Wqkv = (const float*)d_in[1];
  const float* bqkv = (const float*)d_in[2];
  const float* W1   = (const float*)d_in[3];
  const float* b1   = (const float*)d_in[4];
  const float* W2   = (const float*)d_in[5];
  const float* b2   = (const float*)d_in[6];
  const float* Wp   = (const float*)d_in[7];
  const float* bp   = (const float*)d_in[8];
  kpack<<<dim3(1536), dim3(256), 0, stream>>>(Wqkv, W1, W2, Wp);
  kpool<<<dim3(512),  dim3(512), 0, stream>>>(x);
  kattn<<<dim3(512),  dim3(512), 0, stream>>>(bqkv);
  kout <<<dim3(512),  dim3(512), 0, stream>>>(b1, b2, bp, (float*)d_out);
}

// Round 4
// 188.360 us; speedup vs baseline: 1.1561x; 1.1561x over previous
//
#include <hip/hip_runtime.h>
#include <stdint.h>

// ---------- types ----------
typedef __bf16    bf16x8 __attribute__((ext_vector_type(8)));
typedef float     f32x4  __attribute__((ext_vector_type(4)));
typedef uint32_t  u32x4  __attribute__((ext_vector_type(4)));

#define MFMA(a,b,c) __builtin_amdgcn_mfma_f32_16x16x32_bf16((a),(b),(c),0,0,0)

// ---------- persistent device scratch (bf16 internal pipeline) ----------
__device__ __align__(16) uint16_t g_y [8*64*64*256];
__device__ __align__(16) uint16_t g_wpk[393216];

#define WQF 0
#define WKF 65536
#define WVF 131072
#define WCF 196608
#define W1F 262144
#define W2F 294912
#define WPF 327680

static __device__ __forceinline__ float b2f(uint32_t u){ return __builtin_bit_cast(float, u<<16); }
static __device__ __forceinline__ uint32_t f2b(float f){
  uint32_t x = __builtin_bit_cast(uint32_t, f);
  return (x + 0x7fffu + ((x>>16)&1u)) >> 16;   // RNE bf16
}

// ---------- kernel 0: repack fp32 weights into bf16 B-fragment-major layout ----------
__global__ __launch_bounds__(256) void kpack(const float* __restrict__ Wqkv,
    const float* __restrict__ W1, const float* __restrict__ W2,
    const float* __restrict__ Wp){
  int idx = blockIdx.x*256 + threadIdx.x;
  int j = idx & 7, lane = (idx>>3)&63;
  int n16 = lane & 15, q4 = lane>>4;
  float v;
  if (idx < 262144){                 // q,k,v,chans from interleaved W_qkv (row o = 4c+t)
    int t = idx >> 16, l = idx & 65535;
    int s = (l>>9)&7, nt = l>>12;
    v = Wqkv[(4*(nt*16+n16) + t)*256 + s*32 + q4*8 + j];
  } else if (idx < 294912){          // W1 [128][256]
    int l = idx - 262144;
    int s = (l>>9)&7, nt = l>>12;
    v = W1[(nt*16+n16)*256 + s*32 + q4*8 + j];
  } else if (idx < 327680){          // W2 [256][128], S=4
    int l = idx - 294912;
    int s = (l>>9)&3, nt = l>>11;
    v = W2[(nt*16+n16)*128 + s*32 + q4*8 + j];
  } else {                           // Wp [256][256]
    int l = idx - 327680;
    int s = (l>>9)&7, nt = l>>12;
    v = Wp[(nt*16+n16)*256 + s*32 + q4*8 + j];
  }
  g_wpk[idx] = (uint16_t)f2b(v);
}

// ---------- kernel 1: 3x3 avg pool + NCHW->[pix][C], targeted pad zeroing ----------
__global__ __launch_bounds__(512) void kpool(const float* __restrict__ x){
  __shared__ __align__(16) uint16_t sm[3*256*82];
  uint32_t* smw = (uint32_t*)sm;
  int t = threadIdx.x;
  int b = blockIdx.x >> 6, h = blockIdx.x & 63;
  // zero only pad cols 6/7 and 72/73 of each (plane,c) row
  for (int i=t; i<768; i+=512){
    int base = i*41;                 // (hh*256+c)*41
    smw[base+3]  = 0;
    smw[base+36] = 0;
  }
  // edge blocks: whole OOB plane zeroed
  if (h==0 || h==63){
    int hh = (h==0) ? 0 : 2;
    for (int i=t; i<10496; i+=512) smw[hh*10496 + i] = 0;
  }
  #pragma unroll
  for (int i=0;i<24;i++){
    int id = t + 512*i;                       // 12288 chunks of 4 fp32 elems
    int w4 = id&15, c = (id>>4)&255, hh = id>>12;
    int gy = h - 1 + hh;
    if ((unsigned)gy < 64u){
      f32x4 ld = *(const f32x4*)&x[(((b*256+c)*64+gy)*64) + w4*4];
      int wb = (((hh*256+c)*82 + 8 + w4*4) >> 1);
      smw[wb+0] = f2b(ld[0]) | (f2b(ld[1])<<16);
      smw[wb+1] = f2b(ld[2]) | (f2b(ld[3])<<16);
    }
  }
  __syncthreads();
  int c = t & 255, wsel = t >> 8;
  int r0 = c*82, r1 = r0 + 256*82, r2 = r1 + 256*82;
  int w0 = wsel*32;
  float csp = b2f(sm[r0+w0+7]) + b2f(sm[r1+w0+7]) + b2f(sm[r2+w0+7]);
  float csc = b2f(sm[r0+w0+8]) + b2f(sm[r1+w0+8]) + b2f(sm[r2+w0+8]);
  uint16_t* dst = g_y + ((b*64+h)*64)*256 + c;
  for (int j2=0;j2<32;j2++){
    int w = w0 + j2;
    float csn = b2f(sm[r0+w+9]) + b2f(sm[r1+w+9]) + b2f(sm[r2+w+9]);
    float yv = (csp + csc + csn) * (1.0f/9.0f);
    dst[w*256] = (uint16_t)f2b(yv);
    csp = csc; csc = csn;
  }
}

// ---------- kernel 2: fully fused qkv + attention + chans + gate MLP + proj + out ----------
#define YSTR 264
#define HSTR 134
#define K2_QS 26400
#define K2_KS 34976
#define K2_VS 48376
#define MCH 0          // 64x264 over dead Y rows 0..63
#define MHS 16896      // 64x136 over dead Y rows 64..96
#define MAO 25600      // 64x264 over dead Q/K head
__global__ __launch_bounds__(512,2) void kattn(const float* __restrict__ bqkv,
    const float* __restrict__ b1, const float* __restrict__ b2v,
    const float* __restrict__ bp, float* __restrict__ out){
  __shared__ __align__(16) uint16_t sm[61776];   // 123.5 KB
  int t = threadIdx.x;
  int lane = t & 63, wave = t >> 6;
  int n16 = lane & 15, quad = lane >> 4;
  // swizzled block decode: bids 8 apart share (bb,ty,txp), differ in txl -> same XCD pair
  int bid = blockIdx.x;
  int bb = bid>>6, tyhi=(bid>>4)&3, txl=(bid>>3)&1, tylo=(bid>>2)&1, txp=bid&3;
  int ty = tyhi*2+tylo, tx = txp*2+txl;

  uint32_t opk[2][16];   // packed attention output (waves 0-3)
  uint32_t chp[32];      // packed chans GEMM output (waves 4-7)

  // --- load 10x10 y-halo (zero outside image) ---
  #pragma unroll
  for (int i=0;i<7;i++){
    int id = t + 512*i;
    if (id < 3200){
      int hp = id >> 5, c8 = id & 31;
      int py = hp/10, px = hp - py*10;
      int gy = ty*8 + py - 1, gx = tx*8 + px - 1;
      u32x4 ld = {0,0,0,0};
      if ((unsigned)gy<64u && (unsigned)gx<64u)
        ld = *(const u32x4*)&g_y[((bb*64+gy)*64+gx)*256 + c8*8];
      *(u32x4*)&sm[hp*YSTR + c8*8] = ld;
    }
  }
  __syncthreads();

  #pragma unroll
  for (int hf=0; hf<2; hf++){
    // ---- q GEMM: M=64 interior, N=128 (this half) ----
    {
      int ntg = hf*8 + wave;
      bf16x8 Bq[8];
      #pragma unroll
      for (int s=0;s<8;s++) Bq[s] = *(const bf16x8*)&g_wpk[WQF + ((ntg*8+s)*64+lane)*8];
      float bq = bqkv[4*(ntg*16+n16) + 0];
      int colB = wave*16;
      #pragma unroll
      for (int mt=0; mt<4; mt++){
        f32x4 a = {0.f,0.f,0.f,0.f};
        int m = mt*16 + n16;
        int hrow = 10*(m>>3) + (m&7) + 11;
        #pragma unroll
        for (int s=0;s<8;s++){
          bf16x8 A = *(const bf16x8*)&sm[hrow*YSTR + s*32 + quad*8];
          a = MFMA(A, Bq[s], a);
        }
        #pragma unroll
        for (int r=0;r<4;r++){
          int row = mt*16 + quad*4 + r;
          sm[K2_QS + row*HSTR + colB + n16] = (uint16_t)f2b(a[r] + bq);
        }
      }
    }
    __syncthreads();
    // ---- k & v GEMM (shared A-frags): M=112 halo (rows>=100 clamped), N=128 ----
    {
      int ntg = hf*8 + wave;
      bf16x8 Bk[8], Bv[8];
      #pragma unroll
      for (int s=0;s<8;s++){
        Bk[s] = *(const bf16x8*)&g_wpk[WKF + ((ntg*8+s)*64+lane)*8];
        Bv[s] = *(const bf16x8*)&g_wpk[WVF + ((ntg*8+s)*64+lane)*8];
      }
      float bk = bqkv[4*(ntg*16+n16) + 1];
      float bv = bqkv[4*(ntg*16+n16) + 2];
      int colB = wave*16;
      #pragma unroll
      for (int mt=0; mt<7; mt++){
        f32x4 ak = {0.f,0.f,0.f,0.f}, av = {0.f,0.f,0.f,0.f};
        int m = mt*16 + n16;
        int mr = (m < 100) ? m : 99;
        #pragma unroll
        for (int s=0;s<8;s++){
          bf16x8 A = *(const bf16x8*)&sm[mr*YSTR + s*32 + quad*8];
          ak = MFMA(A, Bk[s], ak);
          av = MFMA(A, Bv[s], av);
        }
        #pragma unroll
        for (int r=0;r<4;r++){
          int row = mt*16 + quad*4 + r;
          if (row < 100){
            int py = row/10, px = row - py*10;
            int gy = ty*8 + py - 1, gx = tx*8 + px - 1;
            bool ok = ((unsigned)gy<64u) && ((unsigned)gx<64u);
            float vk = ok ? ak[r] + bk : 0.f;
            float vv = ok ? av[r] + bv : 0.f;
            sm[K2_KS + row*HSTR + colB + n16] = (uint16_t)f2b(vk);
            sm[K2_VS + row*HSTR + colB + n16] = (uint16_t)f2b(vv);
          }
        }
      }
    }
    __syncthreads();
    if (wave < 4){
      // ---- attention: thread=(pixel, 32-col group); softmax over 9 (incl. zeros) ----
      int p = t & 63, hl = wave;
      int iy = p >> 3, ix = p & 7;
      int cb = hl*32;
      const uint32_t* q32 = (const uint32_t*)&sm[K2_QS + p*HSTR + cb];
      float qv[32];
      #pragma unroll
      for (int i=0;i<16;i++){ uint32_t u=q32[i]; qv[2*i]=b2f(u&0xffffu); qv[2*i+1]=b2f(u>>16); }
      int hb = (iy+1)*10 + ix + 1;
      const int off[9] = {-11,-10,-9,-1,0,1,9,10,11};
      float sc[9];
      #pragma unroll
      for (int nb=0;nb<9;nb++){
        const uint32_t* k32 = (const uint32_t*)&sm[K2_KS + (hb+off[nb])*HSTR + cb];
        float s = 0.f;
        #pragma unroll
        for (int i=0;i<16;i++){ uint32_t u=k32[i]; s += qv[2*i]*b2f(u&0xffffu) + qv[2*i+1]*b2f(u>>16); }
        sc[nb] = s * 0.17677669529663687f;
      }
      float mx = sc[0];
      #pragma unroll
      for (int nb=1;nb<9;nb++) mx = fmaxf(mx, sc[nb]);
      float l = 0.f;
      #pragma unroll
      for (int nb=0;nb<9;nb++){ sc[nb] = __expf(sc[nb]-mx); l += sc[nb]; }
      float inv = 1.f / l;
      float o[32];
      #pragma unroll
      for (int i=0;i<32;i++) o[i]=0.f;
      #pragma unroll
      for (int nb=0;nb<9;nb++){
        float wgt = sc[nb]*inv;
        const uint32_t* v32 = (const uint32_t*)&sm[K2_VS + (hb+off[nb])*HSTR + cb];
        #pragma unroll
        for (int i=0;i<16;i++){ uint32_t u=v32[i]; o[2*i] += wgt*b2f(u&0xffffu); o[2*i+1] += wgt*b2f(u>>16); }
      }
      #pragma unroll
      for (int i=0;i<16;i++) opk[hf][i] = f2b(o[2*i]) | (f2b(o[2*i+1])<<16);
    } else if (hf == 0){
      // ---- chans GEMM (concurrent with hf=0 attention): N=256 over waves 4-7 ----
      #pragma unroll
      for (int jj=0;jj<4;jj++){
        int ntg = (wave-4)*4 + jj;
        bf16x8 Bc[8];
        #pragma unroll
        for (int s=0;s<8;s++) Bc[s] = *(const bf16x8*)&g_wpk[WCF + ((ntg*8+s)*64+lane)*8];
        float bc = bqkv[4*(ntg*16+n16) + 3];
        #pragma unroll
        for (int mt=0; mt<4; mt++){
          f32x4 a = {0.f,0.f,0.f,0.f};
          int m = mt*16 + n16;
          int hrow = 10*(m>>3) + (m&7) + 11;
          #pragma unroll
          for (int s=0;s<8;s++){
            bf16x8 A = *(const bf16x8*)&sm[hrow*YSTR + s*32 + quad*8];
            a = MFMA(A, Bc[s], a);
          }
          chp[(jj*4+mt)*2+0] = f2b(a[0]+bc) | (f2b(a[1]+bc)<<16);
          chp[(jj*4+mt)*2+1] = f2b(a[2]+bc) | (f2b(a[3]+bc)<<16);
        }
      }
    } else {
      // ---- hf=1: dump ch regs -> MCH (Y rows 0..63 now dead) ----
      #pragma unroll
      for (int jj=0;jj<4;jj++){
        int ntg = (wave-4)*4 + jj;
        int col = ntg*16 + n16;
        #pragma unroll
        for (int mt=0;mt<4;mt++){
          #pragma unroll
          for (int r2=0;r2<2;r2++){
            uint32_t v = chp[(jj*4+mt)*2+r2];
            int row = mt*16 + quad*4 + r2*2;
            sm[MCH + row*264 + col]     = (uint16_t)(v & 0xffffu);
            sm[MCH + (row+1)*264 + col] = (uint16_t)(v >> 16);
          }
        }
      }
    }
    __syncthreads();
  }
  // ---- dump attention output -> MAO (Q/K dead), then W1 GEMM ----
  if (wave < 4){
    int p = t & 63, cb = wave*32;
    #pragma unroll
    for (int hf=0;hf<2;hf++)
      #pragma unroll
      for (int i=0;i<16;i++)
        *(uint32_t*)&sm[MAO + p*264 + hf*128 + cb + 2*i] = opk[hf][i];
  }
  // h = relu(ch @ W1^T + b1), N=128 (ntg = wave)
  {
    int ntg = wave;
    bf16x8 Bf[8];
    #pragma unroll
    for (int s=0;s<8;s++) Bf[s] = *(const bf16x8*)&g_wpk[W1F + ((ntg*8+s)*64+lane)*8];
    float bs = b1[ntg*16+n16];
    int colB = wave*16;
    #pragma unroll
    for (int mt=0;mt<4;mt++){
      f32x4 a = {0.f,0.f,0.f,0.f};
      #pragma unroll
      for (int s=0;s<8;s++){
        bf16x8 A = *(const bf16x8*)&sm[MCH + (mt*16+n16)*264 + s*32 + quad*8];
        a = MFMA(A, Bf[s], a);
      }
      #pragma unroll
      for (int r=0;r<4;r++){
        int row = mt*16 + quad*4 + r;
        sm[MHS + row*136 + colB + n16] = (uint16_t)f2b(fmaxf(a[r]+bs, 0.f));
      }
    }
  }
  __syncthreads();
  // g = sigmoid(h @ W2^T + b2); t = ao*(1+g) -> MCH (ch dead)
  #pragma unroll
  for (int jj=0;jj<2;jj++){
    int ntg = wave*2 + jj;
    bf16x8 Bf[4];
    #pragma unroll
    for (int s=0;s<4;s++) Bf[s] = *(const bf16x8*)&g_wpk[W2F + ((ntg*4+s)*64+lane)*8];
    float bs = b2v[ntg*16+n16];
    int colB = ntg*16;
    #pragma unroll
    for (int mt=0;mt<4;mt++){
      f32x4 a = {0.f,0.f,0.f,0.f};
      #pragma unroll
      for (int s=0;s<4;s++){
        bf16x8 A = *(const bf16x8*)&sm[MHS + (mt*16+n16)*136 + s*32 + quad*8];
        a = MFMA(A, Bf[s], a);
      }
      #pragma unroll
      for (int r=0;r<4;r++){
        int row = mt*16 + quad*4 + r;
        float gg = 1.f/(1.f+__expf(-(a[r] + bs)));
        float ao = b2f((uint32_t)sm[MAO + row*264 + colB + n16]);
        sm[MCH + row*264 + colB + n16] = (uint16_t)f2b(ao*(1.f+gg));
      }
    }
  }
  __syncthreads();
  // out_t = t @ Wp^T + bp -> MAO (ao dead)
  #pragma unroll
  for (int jj=0;jj<2;jj++){
    int ntg = wave*2 + jj;
    bf16x8 Bf[8];
    #pragma unroll
    for (int s=0;s<8;s++) Bf[s] = *(const bf16x8*)&g_wpk[WPF + ((ntg*8+s)*64+lane)*8];
    float bs = bp[ntg*16+n16];
    int colB = ntg*16;
    #pragma unroll
    for (int mt=0;mt<4;mt++){
      f32x4 a = {0.f,0.f,0.f,0.f};
      #pragma unroll
      for (int s=0;s<8;s++){
        bf16x8 A = *(const bf16x8*)&sm[MCH + (mt*16+n16)*264 + s*32 + quad*8];
        a = MFMA(A, Bf[s], a);
      }
      #pragma unroll
      for (int r=0;r<4;r++){
        int row = mt*16 + quad*4 + r;
        sm[MAO + row*264 + colB + n16] = (uint16_t)f2b(a[r]+bs);
      }
    }
  }
  __syncthreads();
  // fp32 NCHW write: task=(c, iy, ix4), float4 over 4 w
  #pragma unroll
  for (int i=0;i<8;i++){
    int idx = t + 512*i;                // 4096 tasks
    int ix4 = idx&1, iy = (idx>>1)&7, c = idx>>4;
    f32x4 stv;
    #pragma unroll
    for (int j=0;j<4;j++){
      int p = iy*8 + ix4*4 + j;
      stv[j] = b2f((uint32_t)sm[MAO + p*264 + c]);
    }
    *(f32x4*)&out[(((bb*256+c)*64) + ty*8+iy)*64 + tx*8 + ix4*4] = stv;
  }
}

extern "C" void kernel_launch(void* const* d_in, const int* in_sizes, int n_in,
                              void* d_out, int out_size, void* d_ws, size_t ws_size,
                              hipStream_t stream){
  (void)in_sizes; (void)n_in; (void)d_ws; (void)ws_size; (void)out_size;
  const float* x    = (const float*)d_in[0];
  const float* Wqkv = (const float*)d_in[1];
  const float* bqkv = (const float*)d_in[2];
  const float* W1   = (const float*)d_in[3];
  const float* b1   = (const float*)d_in[4];
  const float* W2   = (const float*)d_in[5];
  const float* b2   = (const float*)d_in[6];
  const float* Wp   = (const float*)d_in[7];
  const float* bp   = (const float*)d_in[8];
  kpack<<<dim3(1536), dim3(256), 0, stream>>>(Wqkv, W1, W2, Wp);
  kpool<<<dim3(512),  dim3(512), 0, stream>>>(x);
  kattn<<<dim3(512),  dim3(512), 0, stream>>>(bqkv, b1, b2, bp, (float*)d_out);
}